// Round 8
// baseline (748.110 us; speedup 1.0000x reference)
//
#include <hip/hip_runtime.h>
#include <hip/hip_fp16.h>

#define N_NODES 100000
#define N_EDGES 1600000
#define HIDDEN 64
#define RPB 128                                  // rows per bucket
#define NCB ((N_NODES + RPB - 1) / RPB)          // 782 buckets
#define CAP 2304                                 // padded bucket capacity (mean 2046 + 5.7 sigma)
#define NSEG 256                                 // col-sort counters (key = col>>9 in [0,196))
#define R1_BATCH 4096
#define R1_PER_T (R1_BATCH / 256)                // 16 edges per thread

// ---------------- P0: convert x to fp16 (streaming, RNE) ---------------------------
__global__ void __launch_bounds__(256) conv_fp16_kernel(const float4* __restrict__ x4,
                                                        ushort4* __restrict__ xh,
                                                        int n4) {
    int i = blockIdx.x * blockDim.x + threadIdx.x;
    const int stride = gridDim.x * blockDim.x;
    for (; i < n4; i += stride) {
        const float4 v = x4[i];
        ushort4 q;
        q.x = __half_as_ushort(__float2half(v.x));
        q.y = __half_as_ushort(__float2half(v.y));
        q.z = __half_as_ushort(__float2half(v.z));
        q.w = __half_as_ushort(__float2half(v.w));
        xh[i] = q;
    }
}

// ---------------- P1: coarse scatter into 782 padded row-buckets -------------------
// pack: m.x = (row&127)<<17 | col   (col < 2^17), m.y = val bits
__global__ void __launch_bounds__(256) coarse_scatter_pad_kernel(
        const int* __restrict__ rows, const int* __restrict__ cols,
        const float* __restrict__ vals, int* __restrict__ ccursor,
        int2* __restrict__ cbuf) {
    __shared__ int hist[NCB];
    __shared__ int base[NCB];
    __shared__ int lcur[NCB];
    const int t = threadIdx.x;
    const int b0 = blockIdx.x * R1_BATCH;
    for (int i = t; i < NCB; i += 256) { hist[i] = 0; lcur[i] = 0; }
    __syncthreads();

    int  mb[R1_PER_T];
    int2 md[R1_PER_T];
    #pragma unroll
    for (int k = 0; k < R1_PER_T; ++k) {
        const int e = b0 + k * 256 + t;  // coalesced
        if (e < N_EDGES) {
            const int r = rows[e];
            mb[k] = r >> 7;
            md[k] = make_int2(((r & (RPB - 1)) << 17) | cols[e], __float_as_int(vals[e]));
            atomicAdd(&hist[mb[k]], 1);
        } else {
            mb[k] = -1;
        }
    }
    __syncthreads();
    for (int i = t; i < NCB; i += 256) {
        const int c = hist[i];
        base[i] = c ? (i * CAP + atomicAdd(&ccursor[i], c)) : 0;
    }
    __syncthreads();
    #pragma unroll
    for (int k = 0; k < R1_PER_T; ++k) {
        if (mb[k] >= 0) {
            const int rank = atomicAdd(&lcur[mb[k]], 1);
            cbuf[base[mb[k]] + rank] = md[k];
        }
    }
}

// ---------------- P2: exclusive scan of 782 bucket counts --------------------------
__global__ void __launch_bounds__(1024) count_scan_kernel(const int* __restrict__ ccursor,
                                                          int* __restrict__ cbase) {
    __shared__ int s[2][1024];
    const int t = threadIdx.x;
    s[0][t] = (t < NCB) ? ccursor[t] : 0;
    __syncthreads();
    int src = 0;
    for (int off = 1; off < 1024; off <<= 1) {
        s[1 - src][t] = s[src][t] + (t >= off ? s[src][t - off] : 0);
        __syncthreads();
        src ^= 1;
    }
    if (t <= NCB) cbase[t] = t ? s[src][t - 1] : 0;
}

// ---------------- P3: per-bucket col-segment sort (key = col>>9) -------------------
__global__ void __launch_bounds__(512) fine_colsort_kernel(
        const int2* __restrict__ cbuf, const int* __restrict__ ccursor,
        const int* __restrict__ cbase, int2* __restrict__ ebuf) {
    __shared__ int2 stage[CAP];
    __shared__ int s[2][NSEG];
    __shared__ int lcur[NSEG];
    const int b = blockIdx.x;
    const int t = threadIdx.x;
    const int cnt  = ccursor[b];
    const int src0 = b * CAP;
    const int dst0 = cbase[b];
    for (int i = t; i < NSEG; i += 512) s[0][i] = 0;
    __syncthreads();
    for (int i = t; i < cnt; i += 512) {          // stage + histogram
        const int2 m = cbuf[src0 + i];
        stage[i] = m;
        atomicAdd(&s[0][(m.x & 0x1FFFF) >> 9], 1);
    }
    __syncthreads();
    int src = 0;
    for (int off = 1; off < NSEG; off <<= 1) {
        if (t < NSEG) s[1 - src][t] = s[src][t] + (t >= off ? s[src][t - off] : 0);
        __syncthreads();
        src ^= 1;
    }
    if (t < NSEG) lcur[t] = dst0 + (t ? s[src][t - 1] : 0);
    __syncthreads();
    for (int i = t; i < cnt; i += 512) {          // scatter col-sorted, compact
        const int2 m = stage[i];
        const int pos = atomicAdd(&lcur[(m.x & 0x1FFFF) >> 9], 1);
        ebuf[pos] = m;
    }
}

// ---------------- P4: per-bucket SpMM, LDS fp32 accumulate, fused ReLU -------------
// lane = g*16 + h: g = edge subgroup (0..3), h covers hidden[4h..4h+3]
template <bool FP16>
__global__ void __launch_bounds__(512) spmm_bucket_kernel(
        const ushort4* __restrict__ xh, const float4* __restrict__ x4,
        const int2* __restrict__ ebuf, const int* __restrict__ cbase,
        float4* __restrict__ out4) {
    __shared__ float acc[RPB * 65];               // stride 65: spreads atomic banks
    const int b = blockIdx.x;
    const int t = threadIdx.x;
    const int lane = t & 63;
    const int wave = t >> 6;                      // 8 waves
    const int g = lane >> 4;
    const int h = lane & 15;
    const int bstart = cbase[b];
    const int cnt = cbase[b + 1] - bstart;

    for (int i = t; i < RPB * 65; i += 512) acc[i] = 0.0f;
    __syncthreads();

    const int nchunk = (cnt + 63) >> 6;
    for (int c = wave; c < nchunk; c += 8) {
        const int base = c << 6;
        const int take = min(64, cnt - base);
        int2 m = make_int2(0, 0);
        if (base + lane < cnt) m = ebuf[bstart + base + lane];  // coalesced meta
        for (int j = 0; j < take; j += 8) {
            const int j0 = j + g;
            const int j1 = j + 4 + g;
            const bool p0 = j0 < take;
            const bool p1 = j1 < take;
            const int   mx0 = __shfl(m.x, j0);
            const float v0  = __int_as_float(__shfl(m.y, j0));
            const int   mx1 = __shfl(m.x, j1);
            const float v1  = __int_as_float(__shfl(m.y, j1));
            const int c0 = mx0 & 0x1FFFF;
            const int c1 = mx1 & 0x1FFFF;
            const int r0 = (mx0 >> 17) & (RPB - 1);
            const int r1 = (mx1 >> 17) & (RPB - 1);
            float a0, a1, a2, a3, b0f, b1f, b2f, b3f;
            if (FP16) {
                const ushort4 qa = xh[(size_t)c0 * 16 + h];
                const ushort4 qb = xh[(size_t)c1 * 16 + h];
                a0 = __half2float(__ushort_as_half(qa.x));
                a1 = __half2float(__ushort_as_half(qa.y));
                a2 = __half2float(__ushort_as_half(qa.z));
                a3 = __half2float(__ushort_as_half(qa.w));
                b0f = __half2float(__ushort_as_half(qb.x));
                b1f = __half2float(__ushort_as_half(qb.y));
                b2f = __half2float(__ushort_as_half(qb.z));
                b3f = __half2float(__ushort_as_half(qb.w));
            } else {
                const float4 qa = x4[(size_t)c0 * 16 + h];
                const float4 qb = x4[(size_t)c1 * 16 + h];
                a0 = qa.x; a1 = qa.y; a2 = qa.z; a3 = qa.w;
                b0f = qb.x; b1f = qb.y; b2f = qb.z; b3f = qb.w;
            }
            if (p0) {
                float* p = &acc[r0 * 65 + 4 * h];
                atomicAdd(p + 0, v0 * a0);
                atomicAdd(p + 1, v0 * a1);
                atomicAdd(p + 2, v0 * a2);
                atomicAdd(p + 3, v0 * a3);
            }
            if (p1) {
                float* p = &acc[r1 * 65 + 4 * h];
                atomicAdd(p + 0, v1 * b0f);
                atomicAdd(p + 1, v1 * b1f);
                atomicAdd(p + 2, v1 * b2f);
                atomicAdd(p + 3, v1 * b3f);
            }
        }
    }
    __syncthreads();

    const int rowbase = b * RPB;
    for (int i = t; i < RPB * 16; i += 512) {
        const int row = i >> 4;
        const int hh  = i & 15;
        const int grow = rowbase + row;
        if (grow < N_NODES) {
            const float* a = &acc[row * 65 + 4 * hh];
            float4 o;
            o.x = fmaxf(a[0], 0.f); o.y = fmaxf(a[1], 0.f);
            o.z = fmaxf(a[2], 0.f); o.w = fmaxf(a[3], 0.f);
            out4[(size_t)grow * 16 + hh] = o;
        }
    }
}

// ================= Fallback: global-atomic scatter =================
__global__ void spmm_scatter_kernel(const float* __restrict__ x,
                                    const int* __restrict__ rows,
                                    const int* __restrict__ cols,
                                    const float* __restrict__ vals,
                                    float* __restrict__ f) {
    const int lane = threadIdx.x & 63;
    const int wave = (blockIdx.x * blockDim.x + threadIdx.x) >> 6;
    const int nWaves = (gridDim.x * blockDim.x) >> 6;
    for (int e = wave; e < N_EDGES; e += nWaves)
        atomicAdd(&f[rows[e] * HIDDEN + lane], vals[e] * x[cols[e] * HIDDEN + lane]);
}
__global__ void relu_inplace_kernel(float4* __restrict__ f, int n4) {
    int i = blockIdx.x * blockDim.x + threadIdx.x;
    const int stride = gridDim.x * blockDim.x;
    for (; i < n4; i += stride) {
        float4 v = f[i];
        v.x = fmaxf(v.x, 0.0f); v.y = fmaxf(v.y, 0.0f);
        v.z = fmaxf(v.z, 0.0f); v.w = fmaxf(v.w, 0.0f);
        f[i] = v;
    }
}

extern "C" void kernel_launch(void* const* d_in, const int* in_sizes, int n_in,
                              void* d_out, int out_size, void* d_ws, size_t ws_size,
                              hipStream_t stream) {
    const float* x    = (const float*)d_in[1];
    const int*   rows = (const int*)d_in[2];
    const int*   cols = (const int*)d_in[3];
    const float* vals = (const float*)d_in[4];
    float* out = (float*)d_out;
    char* ws = (char*)d_ws;

    // ws layout: ccursor[NCB] | cbase[NCB+1] | cbuf[NCB*CAP] | ebuf[E] | xh[N*H]
    const size_t ccursor_off = 0;
    const size_t cbase_off   = ccursor_off + (size_t)NCB * 4;
    size_t cbuf_off = cbase_off + (size_t)(NCB + 1) * 4;
    cbuf_off = (cbuf_off + 15) & ~(size_t)15;
    const size_t ebuf_off = cbuf_off + (size_t)NCB * CAP * 8;
    const size_t xh_off   = ebuf_off + (size_t)N_EDGES * 8;
    const size_t ws_t2 = xh_off;                                   // fp32 gather path
    const size_t ws_t1 = xh_off + (size_t)N_NODES * HIDDEN * 2;    // + fp16 x

    if (ws_size >= ws_t2) {
        int*  ccursor = (int*)(ws + ccursor_off);
        int*  cbase   = (int*)(ws + cbase_off);
        int2* cbuf    = (int2*)(ws + cbuf_off);
        int2* ebuf    = (int2*)(ws + ebuf_off);
        const bool fp16_path = (ws_size >= ws_t1);

        hipMemsetAsync(ccursor, 0, (size_t)NCB * 4, stream);
        if (fp16_path) {
            ushort4* xh = (ushort4*)(ws + xh_off);
            conv_fp16_kernel<<<2048, 256, 0, stream>>>((const float4*)x, xh,
                                                       N_NODES * HIDDEN / 4);
        }
        coarse_scatter_pad_kernel<<<(N_EDGES + R1_BATCH - 1) / R1_BATCH, 256, 0, stream>>>(
            rows, cols, vals, ccursor, cbuf);
        count_scan_kernel<<<1, 1024, 0, stream>>>(ccursor, cbase);
        fine_colsort_kernel<<<NCB, 512, 0, stream>>>(cbuf, ccursor, cbase, ebuf);
        if (fp16_path) {
            const ushort4* xh = (const ushort4*)(ws + xh_off);
            spmm_bucket_kernel<true><<<NCB, 512, 0, stream>>>(
                xh, (const float4*)x, ebuf, cbase, (float4*)out);
        } else {
            spmm_bucket_kernel<false><<<NCB, 512, 0, stream>>>(
                (const ushort4*)nullptr, (const float4*)x, ebuf, cbase, (float4*)out);
        }
        return;
    }

    // Fallback: global-atomic scatter
    hipMemsetAsync(d_out, 0, (size_t)N_NODES * HIDDEN * sizeof(float), stream);
    spmm_scatter_kernel<<<2048, 256, 0, stream>>>(x, rows, cols, vals, out);
    relu_inplace_kernel<<<2048, 256, 0, stream>>>((float4*)d_out,
                                                  (N_NODES * HIDDEN) / 4);
}

// Round 9
// 736.488 us; speedup vs baseline: 1.0158x; 1.0158x over previous
//
#include <hip/hip_runtime.h>

#define N_NODES 100000
#define N_EDGES 1600000
#define HIDDEN 64
#define NCB98 98                                 // coarse buckets (1024 rows)
#define CAP98 17152                              // mean 16327 + ~6.5 sigma
#define SUBN (NCB98 * 8)                         // 784 sub-buckets (128 rows)
#define NKEY 2048                                // fine sort keys: sub(3b) | col>>9 (8b)
#define R1_BATCH 4096
#define R1_PER_T (R1_BATCH / 256)                // 16 edges per thread

// ---------------- P1: coarse scatter into 98 padded row-buckets --------------------
// pack: m.x = (row&1023)<<17 | col   (col < 2^17), m.y = val bits
__global__ void __launch_bounds__(256) coarse_scatter98_kernel(
        const int* __restrict__ rows, const int* __restrict__ cols,
        const float* __restrict__ vals, int* __restrict__ ccursor,
        int2* __restrict__ cbuf) {
    __shared__ int hist[NCB98];
    __shared__ int base[NCB98];
    __shared__ int lcur[NCB98];
    const int t = threadIdx.x;
    const int b0 = blockIdx.x * R1_BATCH;
    if (t < NCB98) { hist[t] = 0; lcur[t] = 0; }
    __syncthreads();

    int  mb[R1_PER_T];
    int2 md[R1_PER_T];
    #pragma unroll
    for (int k = 0; k < R1_PER_T; ++k) {
        const int e = b0 + k * 256 + t;  // coalesced
        if (e < N_EDGES) {
            const int r = rows[e];
            mb[k] = r >> 10;
            md[k] = make_int2(((r & 1023) << 17) | cols[e], __float_as_int(vals[e]));
            atomicAdd(&hist[mb[k]], 1);
        } else {
            mb[k] = -1;
        }
    }
    __syncthreads();
    if (t < NCB98) {
        const int c = hist[t];
        base[t] = c ? (t * CAP98 + atomicAdd(&ccursor[t], c)) : 0;
    }
    __syncthreads();
    #pragma unroll
    for (int k = 0; k < R1_PER_T; ++k) {
        if (mb[k] >= 0) {
            const int rank = atomicAdd(&lcur[mb[k]], 1);
            cbuf[base[mb[k]] + rank] = md[k];
        }
    }
}

// ---------------- P2: exclusive scan of 98 bucket counts + sentinel ----------------
__global__ void __launch_bounds__(256) count_scan98_kernel(const int* __restrict__ ccursor,
                                                           int* __restrict__ cbase98,
                                                           int* __restrict__ sbase) {
    __shared__ int s[2][256];
    const int t = threadIdx.x;
    s[0][t] = (t < NCB98) ? ccursor[t] : 0;
    __syncthreads();
    int src = 0;
    for (int off = 1; off < 256; off <<= 1) {
        s[1 - src][t] = s[src][t] + (t >= off ? s[src][t - off] : 0);
        __syncthreads();
        src ^= 1;
    }
    if (t <= NCB98) cbase98[t] = t ? s[src][t - 1] : 0;
    if (t == 0) sbase[SUBN] = N_EDGES;   // sentinel for spmm
}

// ---------------- P3: per-bucket sort by key=(sub,col>>9); writes sbase ------------
// reads cbuf twice (L2-hot); emits ebuf packed (row&127)<<17 | col
__global__ void __launch_bounds__(1024) fine_sub_kernel(
        const int2* __restrict__ cbuf, const int* __restrict__ ccursor,
        const int* __restrict__ cbase98, int* __restrict__ sbase,
        int2* __restrict__ ebuf) {
    __shared__ int s[2][NKEY];     // 16 KB
    __shared__ int lcur[NKEY];     // 8 KB
    const int b = blockIdx.x;
    const int t = threadIdx.x;
    const int cnt  = ccursor[b];
    const int src0 = b * CAP98;
    const int dst0 = cbase98[b];

    s[0][t] = 0; s[0][t + 1024] = 0;
    __syncthreads();
    // pass 1: key histogram
    for (int i = t; i < cnt; i += 1024) {
        const int mx = cbuf[src0 + i].x;
        const int key = (((mx >> 24) & 7) << 8) | ((mx & 0x1FFFF) >> 9);
        atomicAdd(&s[0][key], 1);
    }
    __syncthreads();
    // inclusive scan over 2048 (2 elems/thread, double-buffered)
    int src = 0;
    for (int off = 1; off < NKEY; off <<= 1) {
        const int i0 = t, i1 = t + 1024;
        s[1 - src][i0] = s[src][i0] + (i0 >= off ? s[src][i0 - off] : 0);
        s[1 - src][i1] = s[src][i1] + (i1 >= off ? s[src][i1 - off] : 0);
        __syncthreads();
        src ^= 1;
    }
    // exclusive bases; sub-bucket starts every 256 keys
    for (int k = t; k < NKEY; k += 1024) {
        const int excl = dst0 + (k ? s[src][k - 1] : 0);
        lcur[k] = excl;
        if ((k & 255) == 0) sbase[b * 8 + (k >> 8)] = excl;
    }
    __syncthreads();
    // pass 2: scatter sorted; repack to (row&127)<<17 | col
    for (int i = t; i < cnt; i += 1024) {
        const int2 m = cbuf[src0 + i];
        const int key = (((m.x >> 24) & 7) << 8) | ((m.x & 0x1FFFF) >> 9);
        const int pos = atomicAdd(&lcur[key], 1);
        ebuf[pos] = make_int2(((m.x >> 17) & 127) << 17 | (m.x & 0x1FFFF), m.y);
    }
}

// ---------------- P4: per-sub-bucket SpMM, 1 ds_add_f32 per edge, fused ReLU -------
// acc[r*65 + lane]: banks (r+lane)%32 -> 2-way (free). Metas broadcast via readlane
// (SALU path, keeps LDS pipe for the one atomic per edge).
__global__ void __launch_bounds__(512) spmm_sub_kernel(
        const float* __restrict__ x, const int2* __restrict__ ebuf,
        const int* __restrict__ sbase, float4* __restrict__ out4) {
    __shared__ float acc[128 * 65];               // 33.3 KB
    const int g = blockIdx.x;                     // 0..783
    const int t = threadIdx.x;
    const int lane = t & 63;
    const int w = t >> 6;                         // 8 waves

    for (int i = t; i < 128 * 65; i += 512) acc[i] = 0.0f;
    __syncthreads();

    const int bstart = sbase[g];
    const int bend   = sbase[g + 1];
    const int nchunk = (bend - bstart + 63) >> 6;
    for (int c = w; c < nchunk; c += 8) {         // strided: waves sweep cols together
        const int base = bstart + (c << 6);
        const int take = min(64, bend - base);
        int2 m = make_int2(0, 0);                 // pad edges: v=0 -> harmless add to acc[0]
        if (lane < take) m = ebuf[base + lane];   // coalesced meta load
        const int tk = (take + 3) & ~3;
        for (int j = 0; j < tk; j += 4) {
            const int mx0 = __builtin_amdgcn_readlane(m.x, j);
            const int my0 = __builtin_amdgcn_readlane(m.y, j);
            const int mx1 = __builtin_amdgcn_readlane(m.x, j + 1);
            const int my1 = __builtin_amdgcn_readlane(m.y, j + 1);
            const int mx2 = __builtin_amdgcn_readlane(m.x, j + 2);
            const int my2 = __builtin_amdgcn_readlane(m.y, j + 2);
            const int mx3 = __builtin_amdgcn_readlane(m.x, j + 3);
            const int my3 = __builtin_amdgcn_readlane(m.y, j + 3);
            const float g0 = x[(size_t)(mx0 & 0x1FFFF) * HIDDEN + lane];
            const float g1 = x[(size_t)(mx1 & 0x1FFFF) * HIDDEN + lane];
            const float g2 = x[(size_t)(mx2 & 0x1FFFF) * HIDDEN + lane];
            const float g3 = x[(size_t)(mx3 & 0x1FFFF) * HIDDEN + lane];
            atomicAdd(&acc[((mx0 >> 17) & 127) * 65 + lane], __int_as_float(my0) * g0);
            atomicAdd(&acc[((mx1 >> 17) & 127) * 65 + lane], __int_as_float(my1) * g1);
            atomicAdd(&acc[((mx2 >> 17) & 127) * 65 + lane], __int_as_float(my2) * g2);
            atomicAdd(&acc[((mx3 >> 17) & 127) * 65 + lane], __int_as_float(my3) * g3);
        }
    }
    __syncthreads();

    // epilogue: 128 rows x 16 float4, fused ReLU
    const int rowbase = g << 7;
    for (int i = t; i < 128 * 16; i += 512) {
        const int row = i >> 4, hh = i & 15;
        const int grow = rowbase + row;
        if (grow < N_NODES) {
            const float* a = &acc[row * 65 + 4 * hh];
            float4 o;
            o.x = fmaxf(a[0], 0.f); o.y = fmaxf(a[1], 0.f);
            o.z = fmaxf(a[2], 0.f); o.w = fmaxf(a[3], 0.f);
            out4[(size_t)grow * 16 + hh] = o;
        }
    }
}

// ================= Fallback: global-atomic scatter =================
__global__ void spmm_scatter_kernel(const float* __restrict__ x,
                                    const int* __restrict__ rows,
                                    const int* __restrict__ cols,
                                    const float* __restrict__ vals,
                                    float* __restrict__ f) {
    const int lane = threadIdx.x & 63;
    const int wave = (blockIdx.x * blockDim.x + threadIdx.x) >> 6;
    const int nWaves = (gridDim.x * blockDim.x) >> 6;
    for (int e = wave; e < N_EDGES; e += nWaves)
        atomicAdd(&f[rows[e] * HIDDEN + lane], vals[e] * x[cols[e] * HIDDEN + lane]);
}
__global__ void relu_inplace_kernel(float4* __restrict__ f, int n4) {
    int i = blockIdx.x * blockDim.x + threadIdx.x;
    const int stride = gridDim.x * blockDim.x;
    for (; i < n4; i += stride) {
        float4 v = f[i];
        v.x = fmaxf(v.x, 0.0f); v.y = fmaxf(v.y, 0.0f);
        v.z = fmaxf(v.z, 0.0f); v.w = fmaxf(v.w, 0.0f);
        f[i] = v;
    }
}

extern "C" void kernel_launch(void* const* d_in, const int* in_sizes, int n_in,
                              void* d_out, int out_size, void* d_ws, size_t ws_size,
                              hipStream_t stream) {
    const float* x    = (const float*)d_in[1];
    const int*   rows = (const int*)d_in[2];
    const int*   cols = (const int*)d_in[3];
    const float* vals = (const float*)d_in[4];
    float* out = (float*)d_out;
    char* ws = (char*)d_ws;

    // ws: ccursor[98] | cbase98[99] | sbase[785] | cbuf[98*CAP98] | ebuf[E]
    const size_t ccursor_off = 0;
    const size_t cbase_off   = ccursor_off + (size_t)NCB98 * 4;
    const size_t sbase_off   = cbase_off + (size_t)(NCB98 + 1) * 4;
    size_t cbuf_off = sbase_off + (size_t)(SUBN + 1) * 4;
    cbuf_off = (cbuf_off + 15) & ~(size_t)15;
    const size_t ebuf_off = cbuf_off + (size_t)NCB98 * CAP98 * 8;
    const size_t ws_need  = ebuf_off + (size_t)N_EDGES * 8;

    if (ws_size >= ws_need) {
        int*  ccursor = (int*)(ws + ccursor_off);
        int*  cbase98 = (int*)(ws + cbase_off);
        int*  sbase   = (int*)(ws + sbase_off);
        int2* cbuf    = (int2*)(ws + cbuf_off);
        int2* ebuf    = (int2*)(ws + ebuf_off);

        hipMemsetAsync(ccursor, 0, (size_t)NCB98 * 4, stream);
        coarse_scatter98_kernel<<<(N_EDGES + R1_BATCH - 1) / R1_BATCH, 256, 0, stream>>>(
            rows, cols, vals, ccursor, cbuf);
        count_scan98_kernel<<<1, 256, 0, stream>>>(ccursor, cbase98, sbase);
        fine_sub_kernel<<<NCB98, 1024, 0, stream>>>(cbuf, ccursor, cbase98, sbase, ebuf);
        spmm_sub_kernel<<<SUBN, 512, 0, stream>>>(x, ebuf, sbase, (float4*)out);
        return;
    }

    // Fallback: global-atomic scatter
    hipMemsetAsync(d_out, 0, (size_t)N_NODES * HIDDEN * sizeof(float), stream);
    spmm_scatter_kernel<<<2048, 256, 0, stream>>>(x, rows, cols, vals, out);
    relu_inplace_kernel<<<2048, 256, 0, stream>>>((float4*)d_out,
                                                  (N_NODES * HIDDEN) / 4);
}

// Round 11
// 101.211 us; speedup vs baseline: 7.3916x; 7.2767x over previous
//
#include <hip/hip_runtime.h>
#include <hip/hip_fp16.h>

#define N_NODES 100000
#define N_EDGES 1600000
#define HIDDEN 64
#define RPB 512                                  // rows per bucket
#define NCB ((N_NODES + RPB - 1) / RPB)          // 196 buckets
#define CAP 8960                                 // padded bucket capacity
#define R1_THREADS 512
#define R1_BATCH 6144
#define R1_PER_T (R1_BATCH / R1_THREADS)         // 12 edges per thread
#define FINE_SLOTS 9                             // ceil(CAP / 1024)

// ---------------- P0: convert x to fp16 (streaming, RNE) ---------------------------
__global__ void __launch_bounds__(256) conv_fp16_kernel(const float4* __restrict__ x4,
                                                        ushort4* __restrict__ xh,
                                                        int n4) {
    int i = blockIdx.x * blockDim.x + threadIdx.x;
    const int stride = gridDim.x * blockDim.x;
    for (; i < n4; i += stride) {
        const float4 v = x4[i];
        ushort4 q;
        q.x = __half_as_ushort(__float2half(v.x));
        q.y = __half_as_ushort(__float2half(v.y));
        q.z = __half_as_ushort(__float2half(v.z));
        q.w = __half_as_ushort(__float2half(v.w));
        xh[i] = q;
    }
}

// ---------------- P1: coarse scatter into padded buckets (rank-from-atomic) --------
// pack: m.x = (row&511)<<17 | col   (col < 2^17), m.y = val bits
__global__ void __launch_bounds__(R1_THREADS) coarse_scatter_pad_kernel(
        const int* __restrict__ rows, const int* __restrict__ cols,
        const float* __restrict__ vals, int* __restrict__ ccursor,
        int2* __restrict__ cbuf) {
    __shared__ int hist[NCB];
    __shared__ int base[NCB];
    const int t = threadIdx.x;
    const int b0 = blockIdx.x * R1_BATCH;
    for (int i = t; i < NCB; i += R1_THREADS) hist[i] = 0;
    __syncthreads();

    int  mb[R1_PER_T];
    int  rk[R1_PER_T];
    int2 md[R1_PER_T];
    #pragma unroll
    for (int k = 0; k < R1_PER_T; ++k) {
        const int e = b0 + k * R1_THREADS + t;  // coalesced
        mb[k] = -1;
        if (e < N_EDGES) {
            const int r = rows[e];
            mb[k] = r >> 9;
            md[k] = make_int2(((r & (RPB - 1)) << 17) | cols[e], __float_as_int(vals[e]));
            rk[k] = atomicAdd(&hist[mb[k]], 1);   // local rank, single LDS atomic
        }
    }
    __syncthreads();
    for (int i = t; i < NCB; i += R1_THREADS) {
        const int c = hist[i];
        base[i] = c ? (i * CAP + atomicAdd(&ccursor[i], c)) : 0;
    }
    __syncthreads();
    #pragma unroll
    for (int k = 0; k < R1_PER_T; ++k)
        if (mb[k] >= 0) cbuf[base[mb[k]] + rk[k]] = md[k];
}

// ---------------- P2: exclusive scan of 196 bucket counts --------------------------
__global__ void __launch_bounds__(256) count_scan_kernel(const int* __restrict__ ccursor,
                                                         int* __restrict__ cbase,
                                                         int* __restrict__ offs) {
    __shared__ int s[2][256];
    const int t = threadIdx.x;
    s[0][t] = (t < NCB) ? ccursor[t] : 0;
    __syncthreads();
    int src = 0;
    for (int off = 1; off < 256; off <<= 1) {
        s[1 - src][t] = s[src][t] + (t >= off ? s[src][t - off] : 0);
        __syncthreads();
        src ^= 1;
    }
    if (t <= NCB) cbase[t] = t ? s[src][t - 1] : 0;
    if (t == 0) offs[N_NODES] = N_EDGES;
}

// ---------------- P3: per-bucket row sort, single cbuf read, rank-from-atomic ------
__global__ void __launch_bounds__(1024) fine_bucket_pad_kernel(
        const int2* __restrict__ cbuf, const int* __restrict__ ccursor,
        const int* __restrict__ cbase, int* __restrict__ offs,
        int2* __restrict__ ebuf) {
    __shared__ int s[2][RPB];
    __shared__ int lbase[RPB];
    const int b = blockIdx.x;
    const int t = threadIdx.x;
    const int cnt  = min(ccursor[b], CAP);
    const int src0 = b * CAP;
    const int dst0 = cbase[b];

    if (t < RPB) s[0][t] = 0;
    __syncthreads();

    int  rw[FINE_SLOTS];
    int  rk[FINE_SLOTS];
    int2 md[FINE_SLOTS];
    #pragma unroll
    for (int k = 0; k < FINE_SLOTS; ++k) {
        const int i = k * 1024 + t;
        rw[k] = -1;
        if (i < cnt) {
            const int2 m = cbuf[src0 + i];
            const int row = (m.x >> 17) & (RPB - 1);
            rw[k] = row;
            md[k] = make_int2(m.x & 0x1FFFF, m.y);
            rk[k] = atomicAdd(&s[0][row], 1);     // per-row rank
        }
    }
    __syncthreads();
    int src = 0;
    for (int off = 1; off < RPB; off <<= 1) {
        if (t < RPB) s[1 - src][t] = s[src][t] + (t >= off ? s[src][t - off] : 0);
        __syncthreads();
        src ^= 1;
    }
    if (t < RPB) {
        const int excl = dst0 + (t ? s[src][t - 1] : 0);
        lbase[t] = excl;
        const int row = (b << 9) + t;
        if (row < N_NODES) offs[row] = excl;      // CSR offsets emitted here
    }
    __syncthreads();
    #pragma unroll
    for (int k = 0; k < FINE_SLOTS; ++k)
        if (rw[k] >= 0) ebuf[lbase[rw[k]] + rk[k]] = md[k];
}

// ---------------- P4: CSR SpMM, fp16 gather, ILP-4, fused ReLU ---------------------
// lane = g*16 + h. ALL shfls unconditional (full-EXEC ds_bpermute); lanes >= take
// hold m=(0,0), so pad edges contribute v=0 -> fmaf is a no-op. Shfl idx <= 63 always.
__global__ void __launch_bounds__(256) spmm_csr_relu_h4_kernel(
        const ushort4* __restrict__ xh, const int2* __restrict__ ebuf,
        const int* __restrict__ offs, float4* __restrict__ out4) {
    const int lane = threadIdx.x & 63;
    const int g = lane >> 4;
    const int h = lane & 15;
    const int wave = threadIdx.x >> 6;
    const int r = blockIdx.x * 4 + wave;
    if (r >= N_NODES) return;
    const int start = offs[r];
    const int n = offs[r + 1] - start;

    float4 acc = make_float4(0.f, 0.f, 0.f, 0.f);
    for (int base = 0; base < n; base += 64) {
        const int take = min(64, n - base);
        int2 m = make_int2(0, 0);
        if (base + lane < n) m = ebuf[start + base + lane];  // coalesced meta load
        for (int j = 0; j < take; j += 16) {
            const int i0 = j + g, i1 = j + 4 + g, i2 = j + 8 + g, i3 = j + 12 + g;
            const int   c0 = __shfl(m.x, i0);
            const float v0 = __int_as_float(__shfl(m.y, i0));
            const int   c1 = __shfl(m.x, i1);
            const float v1 = __int_as_float(__shfl(m.y, i1));
            const int   c2 = __shfl(m.x, i2);
            const float v2 = __int_as_float(__shfl(m.y, i2));
            const int   c3 = __shfl(m.x, i3);
            const float v3 = __int_as_float(__shfl(m.y, i3));
            const ushort4 qa = xh[(size_t)c0 * 16 + h];   // 4 loads in flight
            const ushort4 qb = xh[(size_t)c1 * 16 + h];
            const ushort4 qc = xh[(size_t)c2 * 16 + h];
            const ushort4 qd = xh[(size_t)c3 * 16 + h];
            acc.x = fmaf(v0, __half2float(__ushort_as_half(qa.x)), acc.x);
            acc.y = fmaf(v0, __half2float(__ushort_as_half(qa.y)), acc.y);
            acc.z = fmaf(v0, __half2float(__ushort_as_half(qa.z)), acc.z);
            acc.w = fmaf(v0, __half2float(__ushort_as_half(qa.w)), acc.w);
            acc.x = fmaf(v1, __half2float(__ushort_as_half(qb.x)), acc.x);
            acc.y = fmaf(v1, __half2float(__ushort_as_half(qb.y)), acc.y);
            acc.z = fmaf(v1, __half2float(__ushort_as_half(qb.z)), acc.z);
            acc.w = fmaf(v1, __half2float(__ushort_as_half(qb.w)), acc.w);
            acc.x = fmaf(v2, __half2float(__ushort_as_half(qc.x)), acc.x);
            acc.y = fmaf(v2, __half2float(__ushort_as_half(qc.y)), acc.y);
            acc.z = fmaf(v2, __half2float(__ushort_as_half(qc.z)), acc.z);
            acc.w = fmaf(v2, __half2float(__ushort_as_half(qc.w)), acc.w);
            acc.x = fmaf(v3, __half2float(__ushort_as_half(qd.x)), acc.x);
            acc.y = fmaf(v3, __half2float(__ushort_as_half(qd.y)), acc.y);
            acc.z = fmaf(v3, __half2float(__ushort_as_half(qd.z)), acc.z);
            acc.w = fmaf(v3, __half2float(__ushort_as_half(qd.w)), acc.w);
        }
    }
    // fold the 4 edge-subgroups (lanes differing in bits 4,5)
    acc.x += __shfl_xor(acc.x, 16); acc.y += __shfl_xor(acc.y, 16);
    acc.z += __shfl_xor(acc.z, 16); acc.w += __shfl_xor(acc.w, 16);
    acc.x += __shfl_xor(acc.x, 32); acc.y += __shfl_xor(acc.y, 32);
    acc.z += __shfl_xor(acc.z, 32); acc.w += __shfl_xor(acc.w, 32);
    if (lane < 16) {
        float4 o;
        o.x = fmaxf(acc.x, 0.f); o.y = fmaxf(acc.y, 0.f);
        o.z = fmaxf(acc.z, 0.f); o.w = fmaxf(acc.w, 0.f);
        out4[(size_t)r * 16 + h] = o;
    }
}

// ---------------- Tier-1b: fp32-gather spmm (shfl hoisted here too) ----------------
__global__ void __launch_bounds__(256) spmm_csr_relu_f4_kernel(
        const float4* __restrict__ x4, const int2* __restrict__ ebuf,
        const int* __restrict__ offs, float4* __restrict__ out4) {
    const int lane = threadIdx.x & 63;
    const int g = lane >> 4;
    const int h = lane & 15;
    const int wave = threadIdx.x >> 6;
    const int r = blockIdx.x * 4 + wave;
    if (r >= N_NODES) return;
    const int start = offs[r];
    const int n = offs[r + 1] - start;

    float4 acc = make_float4(0.f, 0.f, 0.f, 0.f);
    for (int base = 0; base < n; base += 64) {
        const int take = min(64, n - base);
        int2 m = make_int2(0, 0);
        if (base + lane < n) m = ebuf[start + base + lane];
        for (int j = 0; j < take; j += 8) {
            const int j0 = j + g, j1 = j + 4 + g;
            const int   c0 = __shfl(m.x, j0);
            const float v0 = __int_as_float(__shfl(m.y, j0));
            const int   c1 = __shfl(m.x, j1);
            const float v1 = __int_as_float(__shfl(m.y, j1));
            const float4 a  = x4[(size_t)c0 * 16 + h];
            const float4 bq = x4[(size_t)c1 * 16 + h];
            acc.x = fmaf(v0, a.x, acc.x);  acc.y = fmaf(v0, a.y, acc.y);
            acc.z = fmaf(v0, a.z, acc.z);  acc.w = fmaf(v0, a.w, acc.w);
            acc.x = fmaf(v1, bq.x, acc.x); acc.y = fmaf(v1, bq.y, acc.y);
            acc.z = fmaf(v1, bq.z, acc.z); acc.w = fmaf(v1, bq.w, acc.w);
        }
    }
    acc.x += __shfl_xor(acc.x, 16); acc.y += __shfl_xor(acc.y, 16);
    acc.z += __shfl_xor(acc.z, 16); acc.w += __shfl_xor(acc.w, 16);
    acc.x += __shfl_xor(acc.x, 32); acc.y += __shfl_xor(acc.y, 32);
    acc.z += __shfl_xor(acc.z, 32); acc.w += __shfl_xor(acc.w, 32);
    if (lane < 16) {
        float4 o;
        o.x = fmaxf(acc.x, 0.f); o.y = fmaxf(acc.y, 0.f);
        o.z = fmaxf(acc.z, 0.f); o.w = fmaxf(acc.w, 0.f);
        out4[(size_t)r * 16 + h] = o;
    }
}

// ================= Tier-3 fallback =================
__global__ void spmm_scatter_kernel(const float* __restrict__ x,
                                    const int* __restrict__ rows,
                                    const int* __restrict__ cols,
                                    const float* __restrict__ vals,
                                    float* __restrict__ f) {
    const int lane = threadIdx.x & 63;
    const int wave = (blockIdx.x * blockDim.x + threadIdx.x) >> 6;
    const int nWaves = (gridDim.x * blockDim.x) >> 6;
    for (int e = wave; e < N_EDGES; e += nWaves)
        atomicAdd(&f[rows[e] * HIDDEN + lane], vals[e] * x[cols[e] * HIDDEN + lane]);
}
__global__ void relu_inplace_kernel(float4* __restrict__ f, int n4) {
    int i = blockIdx.x * blockDim.x + threadIdx.x;
    const int stride = gridDim.x * blockDim.x;
    for (; i < n4; i += stride) {
        float4 v = f[i];
        v.x = fmaxf(v.x, 0.0f); v.y = fmaxf(v.y, 0.0f);
        v.z = fmaxf(v.z, 0.0f); v.w = fmaxf(v.w, 0.0f);
        f[i] = v;
    }
}

extern "C" void kernel_launch(void* const* d_in, const int* in_sizes, int n_in,
                              void* d_out, int out_size, void* d_ws, size_t ws_size,
                              hipStream_t stream) {
    const float* x    = (const float*)d_in[1];
    const int*   rows = (const int*)d_in[2];
    const int*   cols = (const int*)d_in[3];
    const float* vals = (const float*)d_in[4];
    float* out = (float*)d_out;
    char* ws = (char*)d_ws;

    // ws: ccursor[NCB] | cbase[NCB+1] | offs[N+1] | cbuf[NCB*CAP] | ebuf[E] | xh[N*H]
    const size_t ccursor_off = 0;
    const size_t cbase_off   = ccursor_off + (size_t)NCB * 4;
    const size_t offs_off    = cbase_off + (size_t)(NCB + 1) * 4;
    size_t cbuf_off = offs_off + (size_t)(N_NODES + 1) * 4;
    cbuf_off = (cbuf_off + 15) & ~(size_t)15;
    const size_t ebuf_off = cbuf_off + (size_t)NCB * CAP * 8;
    const size_t xh_off   = ebuf_off + (size_t)N_EDGES * 8;      // 16B-aligned
    const size_t ws_t1b = xh_off;                                // fp32 gather path
    const size_t ws_t1  = xh_off + (size_t)N_NODES * HIDDEN * 2; // + fp16 x

    if (ws_size >= ws_t1b) {
        int*  ccursor = (int*)(ws + ccursor_off);
        int*  cbase   = (int*)(ws + cbase_off);
        int*  offs    = (int*)(ws + offs_off);
        int2* cbuf    = (int2*)(ws + cbuf_off);
        int2* ebuf    = (int2*)(ws + ebuf_off);
        const bool fp16_path = (ws_size >= ws_t1);

        hipMemsetAsync(ccursor, 0, (size_t)NCB * 4, stream);
        if (fp16_path) {
            ushort4* xh = (ushort4*)(ws + xh_off);
            conv_fp16_kernel<<<2048, 256, 0, stream>>>((const float4*)x, xh,
                                                       N_NODES * HIDDEN / 4);
        }
        coarse_scatter_pad_kernel<<<(N_EDGES + R1_BATCH - 1) / R1_BATCH, R1_THREADS,
                                    0, stream>>>(rows, cols, vals, ccursor, cbuf);
        count_scan_kernel<<<1, 256, 0, stream>>>(ccursor, cbase, offs);
        fine_bucket_pad_kernel<<<NCB, 1024, 0, stream>>>(cbuf, ccursor, cbase, offs, ebuf);
        if (fp16_path) {
            const ushort4* xh = (const ushort4*)(ws + xh_off);
            spmm_csr_relu_h4_kernel<<<N_NODES / 4, 256, 0, stream>>>(
                xh, ebuf, offs, (float4*)out);
        } else {
            spmm_csr_relu_f4_kernel<<<N_NODES / 4, 256, 0, stream>>>(
                (const float4*)x, ebuf, offs, (float4*)out);
        }
        return;
    }

    // Tier-3: global-atomic scatter
    hipMemsetAsync(d_out, 0, (size_t)N_NODES * HIDDEN * sizeof(float), stream);
    spmm_scatter_kernel<<<2048, 256, 0, stream>>>(x, rows, cols, vals, out);
    relu_inplace_kernel<<<2048, 256, 0, stream>>>((float4*)d_out,
                                                  (N_NODES * HIDDEN) / 4);
}

// Round 12
// 94.584 us; speedup vs baseline: 7.9095x; 1.0701x over previous
//
#include <hip/hip_runtime.h>
#include <hip/hip_fp16.h>

#define N_NODES 100000
#define N_EDGES 1600000
#define HIDDEN 64
#define RPB 512                                  // rows per bucket
#define NCB ((N_NODES + RPB - 1) / RPB)          // 196 buckets
#define CAP 8960                                 // padded bucket capacity
#define R1_THREADS 512
#define R1_BATCH 6144
#define R1_PER_T (R1_BATCH / R1_THREADS)         // 12 edges per thread
#define FINE_SLOTS 9                             // ceil(CAP / 1024)

// ---------------- P0: convert x to fp16 (streaming) + zero ccursor -----------------
__global__ void __launch_bounds__(256) conv_fp16_zero_kernel(const float4* __restrict__ x4,
                                                             ushort4* __restrict__ xh,
                                                             int* __restrict__ ccursor,
                                                             int n4) {
    if (blockIdx.x == 0 && threadIdx.x < NCB) ccursor[threadIdx.x] = 0;
    int i = blockIdx.x * blockDim.x + threadIdx.x;
    const int stride = gridDim.x * blockDim.x;
    for (; i < n4; i += stride) {
        const float4 v = x4[i];
        ushort4 q;
        q.x = __half_as_ushort(__float2half(v.x));
        q.y = __half_as_ushort(__float2half(v.y));
        q.z = __half_as_ushort(__float2half(v.z));
        q.w = __half_as_ushort(__float2half(v.w));
        xh[i] = q;
    }
}

// ---------------- P1: coarse scatter into padded buckets (rank-from-atomic) --------
// pack: m.x = (row&511)<<17 | col   (col < 2^17), m.y = val bits
__global__ void __launch_bounds__(R1_THREADS) coarse_scatter_pad_kernel(
        const int* __restrict__ rows, const int* __restrict__ cols,
        const float* __restrict__ vals, int* __restrict__ ccursor,
        int2* __restrict__ cbuf) {
    __shared__ int hist[NCB];
    __shared__ int base[NCB];
    const int t = threadIdx.x;
    const int b0 = blockIdx.x * R1_BATCH;
    for (int i = t; i < NCB; i += R1_THREADS) hist[i] = 0;
    __syncthreads();

    int  mb[R1_PER_T];
    int  rk[R1_PER_T];
    int2 md[R1_PER_T];
    #pragma unroll
    for (int k = 0; k < R1_PER_T; ++k) {
        const int e = b0 + k * R1_THREADS + t;  // coalesced
        mb[k] = -1;
        if (e < N_EDGES) {
            const int r = rows[e];
            mb[k] = r >> 9;
            md[k] = make_int2(((r & (RPB - 1)) << 17) | cols[e], __float_as_int(vals[e]));
            rk[k] = atomicAdd(&hist[mb[k]], 1);   // local rank, single LDS atomic
        }
    }
    __syncthreads();
    for (int i = t; i < NCB; i += R1_THREADS) {
        const int c = hist[i];
        base[i] = c ? (i * CAP + atomicAdd(&ccursor[i], c)) : 0;
    }
    __syncthreads();
    #pragma unroll
    for (int k = 0; k < R1_PER_T; ++k)
        if (mb[k] >= 0) cbuf[base[mb[k]] + rk[k]] = md[k];
}

// ---------------- P2: fine = internal 196-scan + row sort + CSR offs ---------------
__global__ void __launch_bounds__(1024) fine_bucket2_kernel(
        const int2* __restrict__ cbuf, const int* __restrict__ ccursor,
        int* __restrict__ offs, int2* __restrict__ ebuf) {
    __shared__ int csc[2][256];
    __shared__ int s[2][RPB];
    __shared__ int lbase[RPB];
    const int b = blockIdx.x;
    const int t = threadIdx.x;

    // in-block exclusive scan of the 196 bucket counts (replaces count_scan kernel)
    if (t < 256) csc[0][t] = (t < NCB) ? ccursor[t] : 0;
    __syncthreads();
    int sc = 0;
    for (int off = 1; off < 256; off <<= 1) {
        if (t < 256) csc[1 - sc][t] = csc[sc][t] + (t >= off ? csc[sc][t - off] : 0);
        __syncthreads();
        sc ^= 1;
    }
    const int dst0 = b ? csc[sc][b - 1] : 0;
    const int cnt  = min(ccursor[b], CAP);
    const int src0 = b * CAP;
    if (b == 0 && t == 0) offs[N_NODES] = N_EDGES;   // sentinel (was in count_scan)

    if (t < RPB) s[0][t] = 0;
    __syncthreads();

    int  rw[FINE_SLOTS];
    int  rk[FINE_SLOTS];
    int2 md[FINE_SLOTS];
    #pragma unroll
    for (int k = 0; k < FINE_SLOTS; ++k) {
        const int i = k * 1024 + t;
        rw[k] = -1;
        if (i < cnt) {
            const int2 m = cbuf[src0 + i];
            const int row = (m.x >> 17) & (RPB - 1);
            rw[k] = row;
            md[k] = make_int2(m.x & 0x1FFFF, m.y);
            rk[k] = atomicAdd(&s[0][row], 1);     // per-row rank
        }
    }
    __syncthreads();
    int src = 0;
    for (int off = 1; off < RPB; off <<= 1) {
        if (t < RPB) s[1 - src][t] = s[src][t] + (t >= off ? s[src][t - off] : 0);
        __syncthreads();
        src ^= 1;
    }
    if (t < RPB) {
        const int excl = dst0 + (t ? s[src][t - 1] : 0);
        lbase[t] = excl;
        const int row = (b << 9) + t;
        if (row < N_NODES) offs[row] = excl;      // CSR offsets emitted here
    }
    __syncthreads();
    #pragma unroll
    for (int k = 0; k < FINE_SLOTS; ++k)
        if (rw[k] >= 0) ebuf[lbase[rw[k]] + rk[k]] = md[k];
}

// ---------------- P3: CSR SpMM, fp16 gather, ILP-4, fused ReLU ---------------------
// lane = g*16 + h. ALL shfls unconditional; lanes >= take hold m=(0,0) -> v=0 no-op.
__global__ void __launch_bounds__(256) spmm_csr_relu_h4_kernel(
        const ushort4* __restrict__ xh, const int2* __restrict__ ebuf,
        const int* __restrict__ offs, float4* __restrict__ out4) {
    const int lane = threadIdx.x & 63;
    const int g = lane >> 4;
    const int h = lane & 15;
    const int wave = threadIdx.x >> 6;
    const int r = blockIdx.x * 4 + wave;
    if (r >= N_NODES) return;
    const int start = offs[r];
    const int n = offs[r + 1] - start;

    float4 acc = make_float4(0.f, 0.f, 0.f, 0.f);
    for (int base = 0; base < n; base += 64) {
        const int take = min(64, n - base);
        int2 m = make_int2(0, 0);
        if (base + lane < n) m = ebuf[start + base + lane];  // coalesced meta load
        for (int j = 0; j < take; j += 16) {
            const int i0 = j + g, i1 = j + 4 + g, i2 = j + 8 + g, i3 = j + 12 + g;
            const int   c0 = __shfl(m.x, i0);
            const float v0 = __int_as_float(__shfl(m.y, i0));
            const int   c1 = __shfl(m.x, i1);
            const float v1 = __int_as_float(__shfl(m.y, i1));
            const int   c2 = __shfl(m.x, i2);
            const float v2 = __int_as_float(__shfl(m.y, i2));
            const int   c3 = __shfl(m.x, i3);
            const float v3 = __int_as_float(__shfl(m.y, i3));
            const ushort4 qa = xh[(size_t)c0 * 16 + h];   // 4 loads in flight
            const ushort4 qb = xh[(size_t)c1 * 16 + h];
            const ushort4 qc = xh[(size_t)c2 * 16 + h];
            const ushort4 qd = xh[(size_t)c3 * 16 + h];
            acc.x = fmaf(v0, __half2float(__ushort_as_half(qa.x)), acc.x);
            acc.y = fmaf(v0, __half2float(__ushort_as_half(qa.y)), acc.y);
            acc.z = fmaf(v0, __half2float(__ushort_as_half(qa.z)), acc.z);
            acc.w = fmaf(v0, __half2float(__ushort_as_half(qa.w)), acc.w);
            acc.x = fmaf(v1, __half2float(__ushort_as_half(qb.x)), acc.x);
            acc.y = fmaf(v1, __half2float(__ushort_as_half(qb.y)), acc.y);
            acc.z = fmaf(v1, __half2float(__ushort_as_half(qb.z)), acc.z);
            acc.w = fmaf(v1, __half2float(__ushort_as_half(qb.w)), acc.w);
            acc.x = fmaf(v2, __half2float(__ushort_as_half(qc.x)), acc.x);
            acc.y = fmaf(v2, __half2float(__ushort_as_half(qc.y)), acc.y);
            acc.z = fmaf(v2, __half2float(__ushort_as_half(qc.z)), acc.z);
            acc.w = fmaf(v2, __half2float(__ushort_as_half(qc.w)), acc.w);
            acc.x = fmaf(v3, __half2float(__ushort_as_half(qd.x)), acc.x);
            acc.y = fmaf(v3, __half2float(__ushort_as_half(qd.y)), acc.y);
            acc.z = fmaf(v3, __half2float(__ushort_as_half(qd.z)), acc.z);
            acc.w = fmaf(v3, __half2float(__ushort_as_half(qd.w)), acc.w);
        }
    }
    acc.x += __shfl_xor(acc.x, 16); acc.y += __shfl_xor(acc.y, 16);
    acc.z += __shfl_xor(acc.z, 16); acc.w += __shfl_xor(acc.w, 16);
    acc.x += __shfl_xor(acc.x, 32); acc.y += __shfl_xor(acc.y, 32);
    acc.z += __shfl_xor(acc.z, 32); acc.w += __shfl_xor(acc.w, 32);
    if (lane < 16) {
        float4 o;
        o.x = fmaxf(acc.x, 0.f); o.y = fmaxf(acc.y, 0.f);
        o.z = fmaxf(acc.z, 0.f); o.w = fmaxf(acc.w, 0.f);
        out4[(size_t)r * 16 + h] = o;
    }
}

// ---------------- Tier-1b: fp32-gather spmm (if no room for xh) --------------------
__global__ void __launch_bounds__(256) spmm_csr_relu_f4_kernel(
        const float4* __restrict__ x4, const int2* __restrict__ ebuf,
        const int* __restrict__ offs, float4* __restrict__ out4) {
    const int lane = threadIdx.x & 63;
    const int g = lane >> 4;
    const int h = lane & 15;
    const int wave = threadIdx.x >> 6;
    const int r = blockIdx.x * 4 + wave;
    if (r >= N_NODES) return;
    const int start = offs[r];
    const int n = offs[r + 1] - start;

    float4 acc = make_float4(0.f, 0.f, 0.f, 0.f);
    for (int base = 0; base < n; base += 64) {
        const int take = min(64, n - base);
        int2 m = make_int2(0, 0);
        if (base + lane < n) m = ebuf[start + base + lane];
        for (int j = 0; j < take; j += 8) {
            const int j0 = j + g, j1 = j + 4 + g;
            const int   c0 = __shfl(m.x, j0);
            const float v0 = __int_as_float(__shfl(m.y, j0));
            const int   c1 = __shfl(m.x, j1);
            const float v1 = __int_as_float(__shfl(m.y, j1));
            const float4 a  = x4[(size_t)c0 * 16 + h];
            const float4 bq = x4[(size_t)c1 * 16 + h];
            acc.x = fmaf(v0, a.x, acc.x);  acc.y = fmaf(v0, a.y, acc.y);
            acc.z = fmaf(v0, a.z, acc.z);  acc.w = fmaf(v0, a.w, acc.w);
            acc.x = fmaf(v1, bq.x, acc.x); acc.y = fmaf(v1, bq.y, acc.y);
            acc.z = fmaf(v1, bq.z, acc.z); acc.w = fmaf(v1, bq.w, acc.w);
        }
    }
    acc.x += __shfl_xor(acc.x, 16); acc.y += __shfl_xor(acc.y, 16);
    acc.z += __shfl_xor(acc.z, 16); acc.w += __shfl_xor(acc.w, 16);
    acc.x += __shfl_xor(acc.x, 32); acc.y += __shfl_xor(acc.y, 32);
    acc.z += __shfl_xor(acc.z, 32); acc.w += __shfl_xor(acc.w, 32);
    if (lane < 16) {
        float4 o;
        o.x = fmaxf(acc.x, 0.f); o.y = fmaxf(acc.y, 0.f);
        o.z = fmaxf(acc.z, 0.f); o.w = fmaxf(acc.w, 0.f);
        out4[(size_t)r * 16 + h] = o;
    }
}

// ================= Tier-3 fallback =================
__global__ void spmm_scatter_kernel(const float* __restrict__ x,
                                    const int* __restrict__ rows,
                                    const int* __restrict__ cols,
                                    const float* __restrict__ vals,
                                    float* __restrict__ f) {
    const int lane = threadIdx.x & 63;
    const int wave = (blockIdx.x * blockDim.x + threadIdx.x) >> 6;
    const int nWaves = (gridDim.x * blockDim.x) >> 6;
    for (int e = wave; e < N_EDGES; e += nWaves)
        atomicAdd(&f[rows[e] * HIDDEN + lane], vals[e] * x[cols[e] * HIDDEN + lane]);
}
__global__ void relu_inplace_kernel(float4* __restrict__ f, int n4) {
    int i = blockIdx.x * blockDim.x + threadIdx.x;
    const int stride = gridDim.x * blockDim.x;
    for (; i < n4; i += stride) {
        float4 v = f[i];
        v.x = fmaxf(v.x, 0.0f); v.y = fmaxf(v.y, 0.0f);
        v.z = fmaxf(v.z, 0.0f); v.w = fmaxf(v.w, 0.0f);
        f[i] = v;
    }
}

extern "C" void kernel_launch(void* const* d_in, const int* in_sizes, int n_in,
                              void* d_out, int out_size, void* d_ws, size_t ws_size,
                              hipStream_t stream) {
    const float* x    = (const float*)d_in[1];
    const int*   rows = (const int*)d_in[2];
    const int*   cols = (const int*)d_in[3];
    const float* vals = (const float*)d_in[4];
    float* out = (float*)d_out;
    char* ws = (char*)d_ws;

    // ws: ccursor[NCB] | offs[N+1] | cbuf[NCB*CAP] | ebuf[E] | xh[N*H]
    const size_t ccursor_off = 0;
    const size_t offs_off    = ccursor_off + (size_t)NCB * 4;
    size_t cbuf_off = offs_off + (size_t)(N_NODES + 1) * 4;
    cbuf_off = (cbuf_off + 15) & ~(size_t)15;
    const size_t ebuf_off = cbuf_off + (size_t)NCB * CAP * 8;
    const size_t xh_off   = ebuf_off + (size_t)N_EDGES * 8;      // 16B-aligned
    const size_t ws_t1b = xh_off;                                // fp32 gather path
    const size_t ws_t1  = xh_off + (size_t)N_NODES * HIDDEN * 2; // + fp16 x

    if (ws_size >= ws_t1b) {
        int*  ccursor = (int*)(ws + ccursor_off);
        int*  offs    = (int*)(ws + offs_off);
        int2* cbuf    = (int2*)(ws + cbuf_off);
        int2* ebuf    = (int2*)(ws + ebuf_off);
        const bool fp16_path = (ws_size >= ws_t1);

        if (fp16_path) {
            ushort4* xh = (ushort4*)(ws + xh_off);
            conv_fp16_zero_kernel<<<2048, 256, 0, stream>>>(
                (const float4*)x, xh, ccursor, N_NODES * HIDDEN / 4);
        } else {
            hipMemsetAsync(ccursor, 0, (size_t)NCB * 4, stream);
        }
        coarse_scatter_pad_kernel<<<(N_EDGES + R1_BATCH - 1) / R1_BATCH, R1_THREADS,
                                    0, stream>>>(rows, cols, vals, ccursor, cbuf);
        fine_bucket2_kernel<<<NCB, 1024, 0, stream>>>(cbuf, ccursor, offs, ebuf);
        if (fp16_path) {
            const ushort4* xh = (const ushort4*)(ws + xh_off);
            spmm_csr_relu_h4_kernel<<<N_NODES / 4, 256, 0, stream>>>(
                xh, ebuf, offs, (float4*)out);
        } else {
            spmm_csr_relu_f4_kernel<<<N_NODES / 4, 256, 0, stream>>>(
                (const float4*)x, ebuf, offs, (float4*)out);
        }
        return;
    }

    // Tier-3: global-atomic scatter
    hipMemsetAsync(d_out, 0, (size_t)N_NODES * HIDDEN * sizeof(float), stream);
    spmm_scatter_kernel<<<2048, 256, 0, stream>>>(x, rows, cols, vals, out);
    relu_inplace_kernel<<<2048, 256, 0, stream>>>((float4*)d_out,
                                                  (N_NODES * HIDDEN) / 4);
}